// Round 12
// baseline (322.272 us; speedup 1.0000x reference)
//
#include <hip/hip_runtime.h>
#include <stdint.h>
#include <limits.h>

// Problem constants (reference: B=4, N=8192, C=64, OUT=64, KNN=36)
#define BB 4
#define NN 8192
#define CC 64
#define OUTD 64
#define KK 36
#define NPTS (BB * NN)          // 32768
#define NBIN 129                // bins 0..128 (0 and 128 are clamp catch-alls)
// t = signed(float_bits(d2)) >> 20 (arith); bin = med3_i32(t,960,1088) - 960.
// Negative d2 (fp rounding) -> t very negative -> bin 0. One integer t per bin.

typedef float v2f __attribute__((ext_vector_type(2)));

static __device__ __forceinline__ int laneid() { return threadIdx.x & 63; }
static __device__ __forceinline__ int waveid_uniform() {
    return __builtin_amdgcn_readfirstlane((int)(threadIdx.x >> 6));
}

// ---------------------------------------------------------------------------
// Kernel 1: v_feat = relu([feature, xyz] @ W_v + b_v)  and pack xyzw=(x,y,z,|p|^2)
// One wave handles 8 points (shares each Wv row load across 8 accumulators).
// Block = 256 = 4 waves = 32 points. grid = NPTS/32 = 1024 blocks.
// ---------------------------------------------------------------------------
__global__ __launch_bounds__(256) void k_vfeat(
    const float* __restrict__ feat, const float* __restrict__ xyz,
    const float* __restrict__ Wv, const float* __restrict__ bv,
    float* __restrict__ vfeat, float4* __restrict__ xyzw)
{
    __shared__ float fb[4][8][64];
    __shared__ float xb[4][8][3];
    const int lane = laneid();
    const int wv = waveid_uniform();
    const int pbase = blockIdx.x * 32 + wv * 8;

    #pragma unroll
    for (int pp = 0; pp < 8; ++pp)
        fb[wv][pp][lane] = feat[(pbase + pp) * CC + lane];
    if (lane < 24)
        xb[wv][lane / 3][lane % 3] = xyz[pbase * 3 + lane];
    // same-wave LDS write->read: in-order per wave, compiler inserts lgkmcnt

    const float b0 = bv[lane];
    float acc[8];
    #pragma unroll
    for (int pp = 0; pp < 8; ++pp) acc[pp] = b0;

    #pragma unroll 4
    for (int c = 0; c < CC; ++c) {
        float w = Wv[c * OUTD + lane];
        #pragma unroll
        for (int pp = 0; pp < 8; ++pp)
            acc[pp] = fmaf(fb[wv][pp][c], w, acc[pp]);
    }
    const float wx = Wv[64 * OUTD + lane];
    const float wy = Wv[65 * OUTD + lane];
    const float wz = Wv[66 * OUTD + lane];
    #pragma unroll
    for (int pp = 0; pp < 8; ++pp) {
        float a = acc[pp];
        a = fmaf(xb[wv][pp][0], wx, a);
        a = fmaf(xb[wv][pp][1], wy, a);
        a = fmaf(xb[wv][pp][2], wz, a);
        vfeat[(pbase + pp) * OUTD + lane] = fmaxf(a, 0.0f);
    }
    if (lane < 8) {
        float x = xb[wv][lane][0], y = xb[wv][lane][1], z = xb[wv][lane][2];
        float sq = (x * x + y * y) + z * z;
        xyzw[pbase + lane] = make_float4(x, y, z, sq);
    }
}

// ---------------------------------------------------------------------------
// Kernel 2: 36-NN via per-query float-bit histogram selection. (R7 structure —
// best measured: 188 us; VALU(~88us)+DS-atomics(~80us) co-bound. Keep SGPR
// <= 64: bigger load windows blow the ~800/SIMD SGPR file, halving occupancy.)
// 512 blocks x 1024 thr, 64 queries/block = lane-per-query, 2 blocks/CU;
// packed candidate pairs (v_pk_fma_f32), AoS float4 via wave-uniform s_load.
// Histogram hist[bin][lane]: bank = lane%32, conflict-free 32-bit counts.
// Tie-break matches lax.top_k: (distance-bits, then smaller index).
// ---------------------------------------------------------------------------
__global__ __launch_bounds__(1024) void k_knn(
    const float4* __restrict__ xyzw, int* __restrict__ idx_ws)
{
    __shared__ __align__(16) uint32_t hist[NBIN * 64];  // 33 KB; reused as buf in pass 2
    __shared__ int binB[64];
    __shared__ int cumLoA[64];
    __shared__ uint32_t bufCnt[64];
    __shared__ uint32_t dirCnt[64];

    const int lane = laneid();
    const int wv = waveid_uniform();               // 0..15
    const int batch = blockIdx.x >> 7;             // 128 blocks per batch
    const int qbase = (blockIdx.x & 127) << 6;
    const int q = qbase + lane;                    // local query id 0..8191
    const float4* __restrict__ xw = xyzw + batch * NN;

    const float4 Q = xw[q];
    const v2f qx = { Q.x, Q.x };
    const v2f qy = { Q.y, Q.y };
    const v2f qz = { Q.z, Q.z };
    const v2f qw = { Q.w, Q.w };
    const v2f m2 = { -2.0f, -2.0f };

    const int j0 = wv * 512;
    const int laneAdj = lane - 960 * 64;           // fold bin rebase into addressing

    for (int i = threadIdx.x; i < NBIN * 64; i += 1024) hist[i] = 0u;
    if (threadIdx.x < 64) { bufCnt[threadIdx.x] = 0u; dirCnt[threadIdx.x] = 0u; }
    __syncthreads();

    // ---- pass 1: histogram of distance bits (2 candidates / iteration) ----
    #pragma unroll 4
    for (int j = j0; j < j0 + 512; j += 2) {
        float4 C0 = xw[j];                         // merged s_load_dwordx8
        float4 C1 = xw[j + 1];
        v2f cx = { C0.x, C1.x }, cy = { C0.y, C1.y };
        v2f cz = { C0.z, C1.z }, cw = { C0.w, C1.w };
        v2f dot = __builtin_elementwise_fma(qx, cx,
                  __builtin_elementwise_fma(qy, cy, qz * cz));
        v2f d2  = __builtin_elementwise_fma(m2, dot, qw + cw);
        int t0 = ((int)__float_as_uint(d2.x)) >> 20;   // arith shift: neg d -> very neg
        int t1 = ((int)__float_as_uint(d2.y)) >> 20;
        int m30 = min(max(t0, 960), 1088);             // v_med3_i32
        int m31 = min(max(t1, 960), 1088);
        atomicAdd(&hist[m30 * 64 + laneAdj], 1u);      // == hist[bin*64 + lane]
        atomicAdd(&hist[m31 * 64 + laneAdj], 1u);
    }
    __syncthreads();

    // ---- find crossing bin (threads 0..63, one query each) ----
    if (threadIdx.x < 64) {
        int cum = 0, Bq = 128, cl = 0;
        for (int b2 = 0; b2 < NBIN; ++b2) {
            int c = (int)hist[b2 * 64 + threadIdx.x];
            if (cum + c >= KK) { Bq = b2; cl = cum; break; }
            cum += c;
        }
        binB[threadIdx.x] = Bq;
        cumLoA[threadIdx.x] = cl;
    }
    __syncthreads();

    // ---- per-lane integer thresholds for pass 2 ----
    // direct (bin < Bq)    <=>  t <  TL
    // boundary (bin == Bq) <=>  !direct && t <= TH
    const int Bq = binB[lane];
    const int TL = (Bq > 0)    ? (960 + Bq) : INT_MIN;
    const int TH = (Bq == 128) ? INT_MAX    : (960 + Bq);
    const int grow = batch * NN + q;

    // buf[pos][lane] (transposed): 64 pos x 64 lanes x 8B = 32 KB (inside hist)
    unsigned long long* buf = (unsigned long long*)hist;

    // ---- pass 2: direct-emit strict members; buffer boundary-bin members ----
    #pragma unroll 4
    for (int j = j0; j < j0 + 512; j += 2) {
        float4 C0 = xw[j];
        float4 C1 = xw[j + 1];
        v2f cx = { C0.x, C1.x }, cy = { C0.y, C1.y };
        v2f cz = { C0.z, C1.z }, cw = { C0.w, C1.w };
        v2f dot = __builtin_elementwise_fma(qx, cx,
                  __builtin_elementwise_fma(qy, cy, qz * cz));
        v2f d2  = __builtin_elementwise_fma(m2, dot, qw + cw);
        int t0 = ((int)__float_as_uint(d2.x)) >> 20;
        int t1 = ((int)__float_as_uint(d2.y)) >> 20;
        if (t0 < TL) {
            uint32_t pos = atomicAdd(&dirCnt[lane], 1u);
            idx_ws[grow * KK + (int)pos] = batch * NN + j;
        } else if (t0 <= TH) {
            uint32_t db = __float_as_uint(fmaxf(d2.x, 0.0f));   // exact monotone key
            uint32_t pos = atomicAdd(&bufCnt[lane], 1u);
            if (pos < 64u) buf[(int)pos * 64 + lane] =
                ((unsigned long long)db << 32) | (uint32_t)j;
        }
        if (t1 < TL) {
            uint32_t pos = atomicAdd(&dirCnt[lane], 1u);
            idx_ws[grow * KK + (int)pos] = batch * NN + (j + 1);
        } else if (t1 <= TH) {
            uint32_t db = __float_as_uint(fmaxf(d2.y, 0.0f));
            uint32_t pos = atomicAdd(&bufCnt[lane], 1u);
            if (pos < 64u) buf[(int)pos * 64 + lane] =
                ((unsigned long long)db << 32) | (uint32_t)(j + 1);
        }
    }
    __syncthreads();

    // ---- final: pick (36 - cumLo) smallest exact keys from boundary bin ----
    if (threadIdx.x < 64) {
        const int t = threadIdx.x;
        const int q2 = qbase + t;
        const int grow2 = batch * NN + q2;
        const int cl = cumLoA[t];
        const int r = KK - cl;
        const int M = min((int)bufCnt[t], 64);
        const int outp = grow2 * KK + cl;
        for (int i = 0; i < r; ++i) {
            unsigned long long best = ~0ULL; int bi = -1;
            for (int u = 0; u < M; ++u) {
                unsigned long long v = buf[u * 64 + t];
                if (v < best) { best = v; bi = u; }
            }
            int jj;
            if (bi >= 0) { buf[bi * 64 + t] = ~0ULL; jj = (int)(best & 0xFFFFFFFFu); }
            else jj = q2;                            // pathological fallback
            if (jj < 0 || jj >= NN) jj = q2;
            idx_ws[outp + i] = batch * NN + jj;
        }
    }
}

// ---------------------------------------------------------------------------
// Kernel 3: attention WITHOUT the projection, and with (near) ZERO LDS.
// Prior version was LDS-pipe-bound (~400 wave-LDS-ops/point ~= 2000 cyc).
// Now: logits via per-lane global row streams (lane k reads neighbor-k row in
// 16-channel register chunks) x F in SGPRs (wave-uniform s_load, v_fma with
// one scalar operand); softmax via shuffles; V weights broadcast by
// v_readlane (no LDS). Writes pre-projection acc INTO d_out (scratch reuse).
// grid = NPTS/4 blocks of 256.
// ---------------------------------------------------------------------------
#define IDX(k) ((((k) & 3) == 0 ? I[(k) >> 2].x : ((k) & 3) == 1 ? I[(k) >> 2].y : \
                 ((k) & 3) == 2 ? I[(k) >> 2].z : I[(k) >> 2].w) & (NPTS - 1))

__global__ __launch_bounds__(256) void k_att(
    const float* __restrict__ feat, const float* __restrict__ vfeat,
    const int* __restrict__ idxw, float* __restrict__ outAcc)
{
    const int lane = laneid();
    const int wv = waveid_uniform();
    const int p = blockIdx.x * 4 + wv;

    // preload all 36 neighbor indices (wave-uniform, for the V-gather loop)
    const int4* __restrict__ myidx4 = (const int4*)(idxw + p * KK);
    int4 I[9];
    #pragma unroll
    for (int t = 0; t < 9; ++t) I[t] = myidx4[t];

    // per-lane neighbor row for the logit phase (lanes >= 36: harmless dup)
    const int jl = idxw[p * KK + (lane < KK ? lane : 0)] & (NPTS - 1);
    const float* __restrict__ Gp = feat + (size_t)jl * CC;
    const float* __restrict__ Fp = feat + (size_t)p * CC;   // uniform -> s_load

    float a = 0.0f;
    #pragma unroll
    for (int ch = 0; ch < 4; ++ch) {
        const float4 g0 = *(const float4*)(Gp + ch * 16 + 0);
        const float4 g1 = *(const float4*)(Gp + ch * 16 + 4);
        const float4 g2 = *(const float4*)(Gp + ch * 16 + 8);
        const float4 g3 = *(const float4*)(Gp + ch * 16 + 12);
        a = fmaf(Fp[ch * 16 +  0], g0.x, a);
        a = fmaf(Fp[ch * 16 +  1], g0.y, a);
        a = fmaf(Fp[ch * 16 +  2], g0.z, a);
        a = fmaf(Fp[ch * 16 +  3], g0.w, a);
        a = fmaf(Fp[ch * 16 +  4], g1.x, a);
        a = fmaf(Fp[ch * 16 +  5], g1.y, a);
        a = fmaf(Fp[ch * 16 +  6], g1.z, a);
        a = fmaf(Fp[ch * 16 +  7], g1.w, a);
        a = fmaf(Fp[ch * 16 +  8], g2.x, a);
        a = fmaf(Fp[ch * 16 +  9], g2.y, a);
        a = fmaf(Fp[ch * 16 + 10], g2.z, a);
        a = fmaf(Fp[ch * 16 + 11], g2.w, a);
        a = fmaf(Fp[ch * 16 + 12], g3.x, a);
        a = fmaf(Fp[ch * 16 + 13], g3.y, a);
        a = fmaf(Fp[ch * 16 + 14], g3.z, a);
        a = fmaf(Fp[ch * 16 + 15], g3.w, a);
    }
    const float logit = (lane < KK) ? a : -1e30f;

    // softmax across the 36 logit lanes
    float m = logit;
    #pragma unroll
    for (int off = 32; off > 0; off >>= 1)
        m = fmaxf(m, __shfl_xor(m, off, 64));
    float e = (lane < KK) ? __expf(logit - m) : 0.0f;
    float s = e;
    #pragma unroll
    for (int off = 32; off > 0; off >>= 1)
        s += __shfl_xor(s, off, 64);
    const float w = e / s;                       // per-lane weight (0 for >=36)

    // weighted V gather: lane = channel; weight broadcast via v_readlane
    float acc = 0.0f;
    #pragma unroll
    for (int k = 0; k < KK; ++k) {
        float wk = __int_as_float(
            __builtin_amdgcn_readlane(__float_as_int(w), k));
        int j = IDX(k);
        acc = fmaf(wk, vfeat[j * OUTD + lane], acc);
    }
    outAcc[(size_t)p * OUTD + lane] = acc;       // pre-projection, into d_out
}

// ---------------------------------------------------------------------------
// Kernel 4: in-place 64x64 projection: out_row = acc_row @ Wsuf + b.
// 4 points per wave share each coalesced L1-hot Wsuf[c][lane] load; acc rows
// via wave-uniform s_load. Same wave reads-then-writes only its own rows.
// grid = NPTS/64 = 512 blocks of 256.
// ---------------------------------------------------------------------------
__global__ __launch_bounds__(256) void k_proj(
    const float* __restrict__ Wsuf, const float* __restrict__ bsuf,
    float* __restrict__ out)
{
    const int lane = laneid();
    const int wv = waveid_uniform();
    const int pbase = blockIdx.x * 64 + wv * 16;
    const float bb = bsuf[lane];

    for (int g = 0; g < 4; ++g) {
        const int p0 = pbase + g * 4;
        const float* __restrict__ A0 = out + (size_t)(p0 + 0) * OUTD;
        const float* __restrict__ A1 = out + (size_t)(p0 + 1) * OUTD;
        const float* __restrict__ A2 = out + (size_t)(p0 + 2) * OUTD;
        const float* __restrict__ A3 = out + (size_t)(p0 + 3) * OUTD;
        float o0 = bb, o1 = bb, o2 = bb, o3 = bb;
        #pragma unroll 8
        for (int c = 0; c < OUTD; ++c) {
            const float wc = Wsuf[c * OUTD + lane];   // coalesced, L1-resident
            o0 = fmaf(A0[c], wc, o0);                 // A*[c]: scalar operands
            o1 = fmaf(A1[c], wc, o1);
            o2 = fmaf(A2[c], wc, o2);
            o3 = fmaf(A3[c], wc, o3);
        }
        out[(size_t)(p0 + 0) * OUTD + lane] = o0;
        out[(size_t)(p0 + 1) * OUTD + lane] = o1;
        out[(size_t)(p0 + 2) * OUTD + lane] = o2;
        out[(size_t)(p0 + 3) * OUTD + lane] = o3;
    }
    if (blockIdx.x == 0 && threadIdx.x == 0)
        out[(size_t)NPTS * OUTD] = (float)NN;     // output 1: scalar N
}

// ---------------------------------------------------------------------------
extern "C" void kernel_launch(void* const* d_in, const int* in_sizes, int n_in,
                              void* d_out, int out_size, void* d_ws, size_t ws_size,
                              hipStream_t stream)
{
    const float* feat = (const float*)d_in[0];
    const float* xyz  = (const float*)d_in[1];
    const float* Wv   = (const float*)d_in[2];
    const float* bv   = (const float*)d_in[3];
    const float* Wsuf = (const float*)d_in[4];
    const float* bsuf = (const float*)d_in[5];
    float* out = (float*)d_out;

    char* ws = (char*)d_ws;
    float4* xyzw = (float4*)ws;                               // 512 KB
    float*  vfeat = (float*)(ws + (512 << 10));               // 8 MB
    int*    idxw  = (int*)(ws + (512 << 10) + (8 << 20));     // 4.5 MB

    k_vfeat<<<NPTS / 32, 256, 0, stream>>>(feat, xyz, Wv, bv, vfeat, xyzw);
    k_knn  <<<NPTS / 64, 1024, 0, stream>>>(xyzw, idxw);
    k_att  <<<NPTS / 4, 256, 0, stream>>>(feat, vfeat, idxw, out);
    k_proj <<<NPTS / 64, 256, 0, stream>>>(Wsuf, bsuf, out);
}

// Round 13
// 292.412 us; speedup vs baseline: 1.1021x; 1.1021x over previous
//
#include <hip/hip_runtime.h>
#include <stdint.h>
#include <limits.h>

// Problem constants (reference: B=4, N=8192, C=64, OUT=64, KNN=36)
#define BB 4
#define NN 8192
#define CC 64
#define OUTD 64
#define KK 36
#define NPTS (BB * NN)          // 32768
#define NBIN 129                // bins 0..128 (0 and 128 are clamp catch-alls)
// t = signed(float_bits(d2)) >> 20 (arith); bin = med3_i32(t,960,1088) - 960.
// Negative d2 (fp rounding) -> t very negative -> bin 0. One integer t per bin.

typedef float v2f __attribute__((ext_vector_type(2)));

static __device__ __forceinline__ int laneid() { return threadIdx.x & 63; }
static __device__ __forceinline__ int waveid_uniform() {
    return __builtin_amdgcn_readfirstlane((int)(threadIdx.x >> 6));
}
static __device__ __forceinline__ float rdlane_f(float v, int l) {
    return __int_as_float(__builtin_amdgcn_readlane(__float_as_int(v), l));
}
// DPP helper: VALU-pipe cross-lane (no LDS). ctrl/bound must be constants.
#define DPP_F(oldv, v, ctrl, bound) \
    __int_as_float(__builtin_amdgcn_update_dpp( \
        __float_as_int(oldv), __float_as_int(v), (ctrl), 0xf, 0xf, (bound)))

// 64-lane sum: result in lane 63 (row_shr prefix + row_bcast combine)
static __device__ __forceinline__ float wave_sum_dpp(float v) {
    v += DPP_F(0.0f, v, 0x111, true);   // row_shr:1
    v += DPP_F(0.0f, v, 0x112, true);   // row_shr:2
    v += DPP_F(0.0f, v, 0x114, true);   // row_shr:4
    v += DPP_F(0.0f, v, 0x118, true);   // row_shr:8
    v += DPP_F(0.0f, v, 0x142, true);   // row_bcast:15
    v += DPP_F(0.0f, v, 0x143, true);   // row_bcast:31
    return rdlane_f(v, 63);
}
// 64-lane max: OOB lanes keep old=v (no-op under max)
static __device__ __forceinline__ float wave_max_dpp(float v) {
    v = fmaxf(v, DPP_F(v, v, 0x111, false));
    v = fmaxf(v, DPP_F(v, v, 0x112, false));
    v = fmaxf(v, DPP_F(v, v, 0x114, false));
    v = fmaxf(v, DPP_F(v, v, 0x118, false));
    v = fmaxf(v, DPP_F(v, v, 0x142, false));
    v = fmaxf(v, DPP_F(v, v, 0x143, false));
    return rdlane_f(v, 63);
}

// ---------------------------------------------------------------------------
// Kernel 1: v_feat = relu([feature, xyz] @ W_v + b_v)  and pack xyzw=(x,y,z,|p|^2)
// One wave handles 8 points (shares each Wv row load across 8 accumulators).
// Block = 256 = 4 waves = 32 points. grid = NPTS/32 = 1024 blocks.
// ---------------------------------------------------------------------------
__global__ __launch_bounds__(256) void k_vfeat(
    const float* __restrict__ feat, const float* __restrict__ xyz,
    const float* __restrict__ Wv, const float* __restrict__ bv,
    float* __restrict__ vfeat, float4* __restrict__ xyzw)
{
    __shared__ float fb[4][8][64];
    __shared__ float xb[4][8][3];
    const int lane = laneid();
    const int wv = waveid_uniform();
    const int pbase = blockIdx.x * 32 + wv * 8;

    #pragma unroll
    for (int pp = 0; pp < 8; ++pp)
        fb[wv][pp][lane] = feat[(pbase + pp) * CC + lane];
    if (lane < 24)
        xb[wv][lane / 3][lane % 3] = xyz[pbase * 3 + lane];
    // same-wave LDS write->read: in-order per wave, compiler inserts lgkmcnt

    const float b0 = bv[lane];
    float acc[8];
    #pragma unroll
    for (int pp = 0; pp < 8; ++pp) acc[pp] = b0;

    #pragma unroll 4
    for (int c = 0; c < CC; ++c) {
        float w = Wv[c * OUTD + lane];
        #pragma unroll
        for (int pp = 0; pp < 8; ++pp)
            acc[pp] = fmaf(fb[wv][pp][c], w, acc[pp]);
    }
    const float wx = Wv[64 * OUTD + lane];
    const float wy = Wv[65 * OUTD + lane];
    const float wz = Wv[66 * OUTD + lane];
    #pragma unroll
    for (int pp = 0; pp < 8; ++pp) {
        float a = acc[pp];
        a = fmaf(xb[wv][pp][0], wx, a);
        a = fmaf(xb[wv][pp][1], wy, a);
        a = fmaf(xb[wv][pp][2], wz, a);
        vfeat[(pbase + pp) * OUTD + lane] = fmaxf(a, 0.0f);
    }
    if (lane < 8) {
        float x = xb[wv][lane][0], y = xb[wv][lane][1], z = xb[wv][lane][2];
        float sq = (x * x + y * y) + z * z;
        xyzw[pbase + lane] = make_float4(x, y, z, sq);
    }
}

// ---------------------------------------------------------------------------
// Kernel 2: 36-NN via per-query float-bit histogram selection. (R7 structure —
// best measured: 186 us; VALU + DS-atomics co-bound. Keep SGPR <= 64.)
// 512 blocks x 1024 thr, 64 queries/block = lane-per-query, 2 blocks/CU;
// packed candidate pairs (v_pk_fma_f32), AoS float4 via wave-uniform s_load.
// Histogram hist[bin][lane]: bank = lane%32, conflict-free 32-bit counts.
// Tie-break matches lax.top_k: (distance-bits, then smaller index).
// ---------------------------------------------------------------------------
__global__ __launch_bounds__(1024) void k_knn(
    const float4* __restrict__ xyzw, int* __restrict__ idx_ws)
{
    __shared__ __align__(16) uint32_t hist[NBIN * 64];  // 33 KB; reused as buf in pass 2
    __shared__ int binB[64];
    __shared__ int cumLoA[64];
    __shared__ uint32_t bufCnt[64];
    __shared__ uint32_t dirCnt[64];

    const int lane = laneid();
    const int wv = waveid_uniform();               // 0..15
    const int batch = blockIdx.x >> 7;             // 128 blocks per batch
    const int qbase = (blockIdx.x & 127) << 6;
    const int q = qbase + lane;                    // local query id 0..8191
    const float4* __restrict__ xw = xyzw + batch * NN;

    const float4 Q = xw[q];
    const v2f qx = { Q.x, Q.x };
    const v2f qy = { Q.y, Q.y };
    const v2f qz = { Q.z, Q.z };
    const v2f qw = { Q.w, Q.w };
    const v2f m2 = { -2.0f, -2.0f };

    const int j0 = wv * 512;
    const int laneAdj = lane - 960 * 64;           // fold bin rebase into addressing

    for (int i = threadIdx.x; i < NBIN * 64; i += 1024) hist[i] = 0u;
    if (threadIdx.x < 64) { bufCnt[threadIdx.x] = 0u; dirCnt[threadIdx.x] = 0u; }
    __syncthreads();

    // ---- pass 1: histogram of distance bits (2 candidates / iteration) ----
    #pragma unroll 4
    for (int j = j0; j < j0 + 512; j += 2) {
        float4 C0 = xw[j];                         // merged s_load_dwordx8
        float4 C1 = xw[j + 1];
        v2f cx = { C0.x, C1.x }, cy = { C0.y, C1.y };
        v2f cz = { C0.z, C1.z }, cw = { C0.w, C1.w };
        v2f dot = __builtin_elementwise_fma(qx, cx,
                  __builtin_elementwise_fma(qy, cy, qz * cz));
        v2f d2  = __builtin_elementwise_fma(m2, dot, qw + cw);
        int t0 = ((int)__float_as_uint(d2.x)) >> 20;   // arith shift: neg d -> very neg
        int t1 = ((int)__float_as_uint(d2.y)) >> 20;
        int m30 = min(max(t0, 960), 1088);             // v_med3_i32
        int m31 = min(max(t1, 960), 1088);
        atomicAdd(&hist[m30 * 64 + laneAdj], 1u);      // == hist[bin*64 + lane]
        atomicAdd(&hist[m31 * 64 + laneAdj], 1u);
    }
    __syncthreads();

    // ---- find crossing bin (threads 0..63, one query each) ----
    if (threadIdx.x < 64) {
        int cum = 0, Bq = 128, cl = 0;
        for (int b2 = 0; b2 < NBIN; ++b2) {
            int c = (int)hist[b2 * 64 + threadIdx.x];
            if (cum + c >= KK) { Bq = b2; cl = cum; break; }
            cum += c;
        }
        binB[threadIdx.x] = Bq;
        cumLoA[threadIdx.x] = cl;
    }
    __syncthreads();

    // ---- per-lane integer thresholds for pass 2 ----
    // direct (bin < Bq)    <=>  t <  TL
    // boundary (bin == Bq) <=>  !direct && t <= TH
    const int Bq = binB[lane];
    const int TL = (Bq > 0)    ? (960 + Bq) : INT_MIN;
    const int TH = (Bq == 128) ? INT_MAX    : (960 + Bq);
    const int grow = batch * NN + q;

    // buf[pos][lane] (transposed): 64 pos x 64 lanes x 8B = 32 KB (inside hist)
    unsigned long long* buf = (unsigned long long*)hist;

    // ---- pass 2: direct-emit strict members; buffer boundary-bin members ----
    #pragma unroll 4
    for (int j = j0; j < j0 + 512; j += 2) {
        float4 C0 = xw[j];
        float4 C1 = xw[j + 1];
        v2f cx = { C0.x, C1.x }, cy = { C0.y, C1.y };
        v2f cz = { C0.z, C1.z }, cw = { C0.w, C1.w };
        v2f dot = __builtin_elementwise_fma(qx, cx,
                  __builtin_elementwise_fma(qy, cy, qz * cz));
        v2f d2  = __builtin_elementwise_fma(m2, dot, qw + cw);
        int t0 = ((int)__float_as_uint(d2.x)) >> 20;
        int t1 = ((int)__float_as_uint(d2.y)) >> 20;
        if (t0 < TL) {
            uint32_t pos = atomicAdd(&dirCnt[lane], 1u);
            idx_ws[grow * KK + (int)pos] = batch * NN + j;
        } else if (t0 <= TH) {
            uint32_t db = __float_as_uint(fmaxf(d2.x, 0.0f));   // exact monotone key
            uint32_t pos = atomicAdd(&bufCnt[lane], 1u);
            if (pos < 64u) buf[(int)pos * 64 + lane] =
                ((unsigned long long)db << 32) | (uint32_t)j;
        }
        if (t1 < TL) {
            uint32_t pos = atomicAdd(&dirCnt[lane], 1u);
            idx_ws[grow * KK + (int)pos] = batch * NN + (j + 1);
        } else if (t1 <= TH) {
            uint32_t db = __float_as_uint(fmaxf(d2.y, 0.0f));
            uint32_t pos = atomicAdd(&bufCnt[lane], 1u);
            if (pos < 64u) buf[(int)pos * 64 + lane] =
                ((unsigned long long)db << 32) | (uint32_t)(j + 1);
        }
    }
    __syncthreads();

    // ---- final: pick (36 - cumLo) smallest exact keys from boundary bin ----
    if (threadIdx.x < 64) {
        const int t = threadIdx.x;
        const int q2 = qbase + t;
        const int grow2 = batch * NN + q2;
        const int cl = cumLoA[t];
        const int r = KK - cl;
        const int M = min((int)bufCnt[t], 64);
        const int outp = grow2 * KK + cl;
        for (int i = 0; i < r; ++i) {
            unsigned long long best = ~0ULL; int bi = -1;
            for (int u = 0; u < M; ++u) {
                unsigned long long v = buf[u * 64 + t];
                if (v < best) { best = v; bi = u; }
            }
            int jj;
            if (bi >= 0) { buf[bi * 64 + t] = ~0ULL; jj = (int)(best & 0xFFFFFFFFu); }
            else jj = q2;                            // pathological fallback
            if (jj < 0 || jj >= NN) jj = q2;
            idx_ws[outp + i] = batch * NN + jj;
        }
    }
}

// ---------------------------------------------------------------------------
// Kernel 3: attention + projection, LDS pipe offloaded to VALU/scalar pipes.
// Only LDS use: G staging (coalesced gather transpose), two half-channel
// rounds G[4][36][33] (~19 KB -> 8 blocks/CU). F comes from SGPRs
// (wave-uniform s_load); softmax via DPP (VALU); attention weights and
// projection broadcasts via v_readlane (VALU). No __syncthreads.
// grid = NPTS/4 blocks of 256, one point per wave.
// ---------------------------------------------------------------------------
#define IDX(k) ((((k) & 3) == 0 ? I[(k) >> 2].x : ((k) & 3) == 1 ? I[(k) >> 2].y : \
                 ((k) & 3) == 2 ? I[(k) >> 2].z : I[(k) >> 2].w) & (NPTS - 1))

__global__ __launch_bounds__(256) void k_att(
    const float* __restrict__ feat, const float* __restrict__ vfeat,
    const int* __restrict__ idxw, const float* __restrict__ Wsuf,
    const float* __restrict__ bsuf, float* __restrict__ out)
{
    __shared__ float G[4][KK][33];   // 19,008 B (stride 33 == 1 mod 32: <=2-way)
    const int lane = laneid();
    const int wv = waveid_uniform();
    const int p = blockIdx.x * 4 + wv;

    // preload all 36 neighbor indices (wave-uniform s_load)
    const int4* __restrict__ myidx4 = (const int4*)(idxw + p * KK);
    int4 I[9];
    #pragma unroll
    for (int t = 0; t < 9; ++t) I[t] = myidx4[t];

    const float* __restrict__ Fp = feat + (size_t)p * CC;  // uniform -> s_load

    const int half = lane >> 5;       // 0: rows 2kk, 1: rows 2kk+1
    const int cpart = lane & 31;      // column within the 32-wide half

    float a = 0.0f;
    #pragma unroll
    for (int h = 0; h < 2; ++h) {
        // stage half h: 18 wave-loads, each covering two rows' 32-col halves
        #pragma unroll
        for (int kk = 0; kk < 18; ++kk) {
            int jrow = half ? IDX(2 * kk + 1) : IDX(2 * kk);
            G[wv][2 * kk + half][cpart] = feat[jrow * CC + h * 32 + cpart];
        }
        // partial logits over this channel half (lane = k < 36); F is scalar
        if (lane < KK) {
            #pragma unroll 8
            for (int c = 0; c < 32; ++c)
                a = fmaf(Fp[h * 32 + c], G[wv][lane][c], a);
        }
    }
    const float logit = (lane < KK) ? a : -1e30f;

    // softmax across the 36 logit lanes — DPP (VALU pipe), no LDS
    const float m = wave_max_dpp(logit);
    const float e = (lane < KK) ? __expf(logit - m) : 0.0f;
    const float s = wave_sum_dpp(e);
    const float w = e * __frcp_rn(s);            // per-lane weight (0 for >=36)

    // weighted V gather: lane = channel; weight broadcast via v_readlane
    float acc = 0.0f;
    #pragma unroll
    for (int k = 0; k < KK; ++k) {
        float wk = rdlane_f(w, k);
        int j = IDX(k);
        acc = fmaf(wk, vfeat[j * OUTD + lane], acc);
    }

    // projection: o[lane] = b[lane] + sum_c acc_c * Wsuf[c][lane]
    // acc_c broadcast via v_readlane (VALU), Wsuf coalesced L1-hot
    float o = bsuf[lane];
    #pragma unroll 8
    for (int c = 0; c < OUTD; ++c) {
        float ac = rdlane_f(acc, c);
        o = fmaf(ac, Wsuf[c * OUTD + lane], o);
    }
    out[(size_t)p * OUTD + lane] = o;

    if (p == 0 && lane == 0) out[(size_t)NPTS * OUTD] = (float)NN;  // scalar N
}

// ---------------------------------------------------------------------------
extern "C" void kernel_launch(void* const* d_in, const int* in_sizes, int n_in,
                              void* d_out, int out_size, void* d_ws, size_t ws_size,
                              hipStream_t stream)
{
    const float* feat = (const float*)d_in[0];
    const float* xyz  = (const float*)d_in[1];
    const float* Wv   = (const float*)d_in[2];
    const float* bv   = (const float*)d_in[3];
    const float* Wsuf = (const float*)d_in[4];
    const float* bsuf = (const float*)d_in[5];
    float* out = (float*)d_out;

    char* ws = (char*)d_ws;
    float4* xyzw = (float4*)ws;                               // 512 KB
    float*  vfeat = (float*)(ws + (512 << 10));               // 8 MB
    int*    idxw  = (int*)(ws + (512 << 10) + (8 << 20));     // 4.5 MB

    k_vfeat<<<NPTS / 32, 256, 0, stream>>>(feat, xyz, Wv, bv, vfeat, xyzw);
    k_knn  <<<NPTS / 64, 1024, 0, stream>>>(xyzw, idxw);
    k_att  <<<NPTS / 4, 256, 0, stream>>>(feat, vfeat, idxw, Wsuf, bsuf, out);
}